// Round 1
// baseline (916.635 us; speedup 1.0000x reference)
//
#include <hip/hip_runtime.h>
#include <hip/hip_bf16.h>

#define NQ   16384
#define Hh   128
#define Ww   128
#define DIM  256
#define CIN  384
#define NH   8
#define NP   4
#define HD   32

// ---------------------------------------------------------------------------
// Generic tiled fp32 GEMM: C[M,N] = op(A) @ op(B) (+ bias) (+ res)
// A_CM: A stored as A[k*lda + m]   (column-major / transposed access)
// else: A stored as A[m*lda + k]
// B_CM: B stored as B[n*ldb + k]   (i.e. (N,K) row-major)
// else: B stored as B[k*ldb + n]
// TRANS: store C[n*M + m] (for final (Nq,C)->(C,Nq) output), bias still per-n
// Assumes M%64==0, K%16==0, N%4==0. N may be non-multiple of 64 (guarded).
// ---------------------------------------------------------------------------
template<bool A_CM, bool B_CM, bool TRANS>
__global__ __launch_bounds__(256)
void mm64(const float* __restrict__ A, const float* __restrict__ B,
          const float* __restrict__ bias, const float* __restrict__ res,
          float* __restrict__ C, int M, int N, int K, int lda, int ldb)
{
    __shared__ float As[16][64];
    __shared__ float Bs[16][64];
    const int tid = threadIdx.x;
    const int tx = tid & 15, ty = tid >> 4;
    const int m0 = blockIdx.y * 64, n0 = blockIdx.x * 64;

    float acc[4][4];
#pragma unroll
    for (int i = 0; i < 4; ++i)
#pragma unroll
        for (int j = 0; j < 4; ++j) acc[i][j] = 0.f;

    for (int k0 = 0; k0 < K; k0 += 16) {
        if (A_CM) {
            const int m = tid & 63, kq = tid >> 6;
#pragma unroll
            for (int i = 0; i < 4; ++i) {
                const int k = kq * 4 + i;
                As[k][m] = A[(size_t)(k0 + k) * lda + (m0 + m)];
            }
        } else {
            const int m = tid >> 2, kq = tid & 3;
            const float4 a4 = *(const float4*)&A[(size_t)(m0 + m) * lda + k0 + kq * 4];
            As[kq * 4 + 0][m] = a4.x;
            As[kq * 4 + 1][m] = a4.y;
            As[kq * 4 + 2][m] = a4.z;
            As[kq * 4 + 3][m] = a4.w;
        }
        if (B_CM) {
            const int n = tid >> 2, kq = tid & 3;
            float4 b4 = make_float4(0.f, 0.f, 0.f, 0.f);
            if (n0 + n < N) b4 = *(const float4*)&B[(size_t)(n0 + n) * ldb + k0 + kq * 4];
            Bs[kq * 4 + 0][n] = b4.x;
            Bs[kq * 4 + 1][n] = b4.y;
            Bs[kq * 4 + 2][n] = b4.z;
            Bs[kq * 4 + 3][n] = b4.w;
        } else {
            const int n = tid & 63, kq = tid >> 6;
#pragma unroll
            for (int i = 0; i < 4; ++i) {
                const int k = kq * 4 + i;
                Bs[k][n] = (n0 + n < N) ? B[(size_t)(k0 + k) * ldb + n0 + n] : 0.f;
            }
        }
        __syncthreads();
#pragma unroll
        for (int kk = 0; kk < 16; ++kk) {
            const float4 av = *(const float4*)&As[kk][ty * 4];
            const float4 bv = *(const float4*)&Bs[kk][tx * 4];
            const float a[4] = {av.x, av.y, av.z, av.w};
            const float b[4] = {bv.x, bv.y, bv.z, bv.w};
#pragma unroll
            for (int i = 0; i < 4; ++i)
#pragma unroll
                for (int j = 0; j < 4; ++j)
                    acc[i][j] = fmaf(a[i], b[j], acc[i][j]);
        }
        __syncthreads();
    }

    if (!TRANS) {
#pragma unroll
        for (int i = 0; i < 4; ++i) {
            const int m = m0 + ty * 4 + i;
            const int n = n0 + tx * 4;
            if (n < N) {
                float4 o;
                float t[4];
#pragma unroll
                for (int j = 0; j < 4; ++j) {
                    float v = acc[i][j];
                    if (bias) v += bias[n + j];
                    if (res) v += res[(size_t)m * N + n + j];
                    t[j] = v;
                }
                o.x = t[0]; o.y = t[1]; o.z = t[2]; o.w = t[3];
                *(float4*)&C[(size_t)m * N + n] = o;
            }
        }
    } else {
#pragma unroll
        for (int j = 0; j < 4; ++j) {
            const int n = n0 + tx * 4 + j;
            if (n < N) {
                const float bv = bias ? bias[n] : 0.f;
                float4 o;
                o.x = acc[0][j] + bv;
                o.y = acc[1][j] + bv;
                o.z = acc[2][j] + bv;
                o.w = acc[3][j] + bv;
                *(float4*)&C[(size_t)n * M + m0 + ty * 4] = o;
            }
        }
    }
}

// pos[pix*256+d] = d<128 ? col_embed[w][d] : row_embed[h][d-128]
__global__ __launch_bounds__(256)
void pos_kernel(const float* __restrict__ row_embed, const float* __restrict__ col_embed,
                float* __restrict__ pos)
{
    const int idx = blockIdx.x * 256 + threadIdx.x;
    const int pix = idx >> 8, d = idx & 255;
    const int h = pix >> 7, w = pix & 127;
    pos[idx] = (d < 128) ? col_embed[w * 128 + d] : row_embed[h * 128 + (d - 128)];
}

__global__ __launch_bounds__(256)
void add_kernel(const float* __restrict__ a, const float* __restrict__ b,
                float* __restrict__ c, int n4)
{
    const int i = blockIdx.x * 256 + threadIdx.x;
    if (i < n4) {
        const float4 x = ((const float4*)a)[i];
        const float4 y = ((const float4*)b)[i];
        float4 o;
        o.x = x.x + y.x; o.y = x.y + y.y; o.z = x.z + y.z; o.w = x.w + y.w;
        ((float4*)c)[i] = o;
    }
}

// in-place softmax over contiguous groups of 4
__global__ __launch_bounds__(256)
void softmax4_kernel(float* __restrict__ aw, int ngroups)
{
    const int g = blockIdx.x * 256 + threadIdx.x;
    if (g >= ngroups) return;
    float4 v = ((const float4*)aw)[g];
    const float m = fmaxf(fmaxf(v.x, v.y), fmaxf(v.z, v.w));
    const float e0 = __expf(v.x - m), e1 = __expf(v.y - m);
    const float e2 = __expf(v.z - m), e3 = __expf(v.w - m);
    const float inv = 1.f / (e0 + e1 + e2 + e3);
    float4 o; o.x = e0 * inv; o.y = e1 * inv; o.z = e2 * inv; o.w = e3 * inv;
    ((float4*)aw)[g] = o;
}

__device__ __forceinline__ float fetch_val(const float* __restrict__ val, int y, int x, int d)
{
    if ((unsigned)y < (unsigned)Hh && (unsigned)x < (unsigned)Ww)
        return val[(size_t)((y << 7) + x) * DIM + d];
    return 0.f;
}

// one block per pixel, one thread per output channel d (= head*32+hd)
__global__ __launch_bounds__(256)
void sample_kernel(const float* __restrict__ val, const float* __restrict__ off,
                   const float* __restrict__ aw, float* __restrict__ out)
{
    const int pix = blockIdx.x;
    const int d = threadIdx.x;
    const int head = d >> 5;
    const float fy = (float)(pix >> 7);
    const float fx = (float)(pix & 127);
    const float* offp = off + (size_t)pix * 64 + head * 8;
    const float* awp = aw + (size_t)pix * 32 + head * 4;
    float accv = 0.f;
#pragma unroll
    for (int p = 0; p < 4; ++p) {
        const float x = fx + offp[p * 2 + 0];
        const float y = fy + offp[p * 2 + 1];
        const float a = awp[p];
        const float x0f = floorf(x), y0f = floorf(y);
        const float lx = x - x0f, ly = y - y0f;
        const int x0 = (int)x0f, y0 = (int)y0f;
        const float w00 = (1.f - lx) * (1.f - ly) * a;
        const float w01 = lx * (1.f - ly) * a;
        const float w10 = (1.f - lx) * ly * a;
        const float w11 = lx * ly * a;
        accv += fetch_val(val, y0,     x0,     d) * w00;
        accv += fetch_val(val, y0,     x0 + 1, d) * w01;
        accv += fetch_val(val, y0 + 1, x0,     d) * w10;
        accv += fetch_val(val, y0 + 1, x0 + 1, d) * w11;
    }
    out[(size_t)pix * DIM + d] = accv;
}

// in-place LayerNorm(+ReLU) over rows of width C (64 or 128), 1 wave per row
template<int C>
__global__ __launch_bounds__(256)
void ln_relu_kernel(float* __restrict__ x, const float* __restrict__ g,
                    const float* __restrict__ b, int rows)
{
    const int row = blockIdx.x * 4 + (threadIdx.x >> 6);
    const int lane = threadIdx.x & 63;
    if (row >= rows) return;
    float* xp = x + (size_t)row * C;
    const float v0 = xp[lane];
    const float v1 = (C > 64) ? xp[lane + 64] : 0.f;
    float s = v0 + v1;
#pragma unroll
    for (int o = 32; o; o >>= 1) s += __shfl_xor(s, o);
    const float mu = s / (float)C;
    const float d0 = v0 - mu;
    const float d1 = (C > 64) ? (v1 - mu) : 0.f;
    float vs = d0 * d0 + d1 * d1;
#pragma unroll
    for (int o = 32; o; o >>= 1) vs += __shfl_xor(vs, o);
    const float rstd = rsqrtf(vs / (float)C + 1e-5f);
    xp[lane] = fmaxf(d0 * rstd * g[lane] + b[lane], 0.f);
    if (C > 64)
        xp[lane + 64] = fmaxf(d1 * rstd * g[lane + 64] + b[lane + 64], 0.f);
}

extern "C" void kernel_launch(void* const* d_in, const int* in_sizes, int n_in,
                              void* d_out, int out_size, void* d_ws, size_t ws_size,
                              hipStream_t stream)
{
    const float* query     = (const float*)d_in[0];
    const float* value     = (const float*)d_in[1];
    const float* conv_q_w  = (const float*)d_in[2];
    const float* conv_q_b  = (const float*)d_in[3];
    const float* conv_v_w  = (const float*)d_in[4];
    const float* conv_v_b  = (const float*)d_in[5];
    const float* row_embed = (const float*)d_in[6];
    const float* col_embed = (const float*)d_in[7];
    const float* lin_q_w   = (const float*)d_in[8];
    const float* lin_q_b   = (const float*)d_in[9];
    const float* lin_v_w   = (const float*)d_in[10];
    const float* lin_v_b   = (const float*)d_in[11];
    const float* off_w     = (const float*)d_in[12];
    const float* off_b     = (const float*)d_in[13];
    const float* aw_w      = (const float*)d_in[14];
    const float* aw_b      = (const float*)d_in[15];
    const float* vp_w      = (const float*)d_in[16];
    const float* vp_b      = (const float*)d_in[17];
    const float* op_w      = (const float*)d_in[18];
    const float* op_b      = (const float*)d_in[19];
    const float* out_w1    = (const float*)d_in[20];
    const float* out_b1    = (const float*)d_in[21];
    const float* ln1_g     = (const float*)d_in[22];
    const float* ln1_b     = (const float*)d_in[23];
    const float* out_w2    = (const float*)d_in[24];
    const float* out_b2    = (const float*)d_in[25];
    const float* ln2_g     = (const float*)d_in[26];
    const float* ln2_b     = (const float*)d_in[27];
    const float* out_w3    = (const float*)d_in[28];
    const float* out_b3    = (const float*)d_in[29];

    float* POS = (float*)d_ws;          // NQ*256
    float* V   = POS + (size_t)NQ * 256;
    float* QA  = V   + (size_t)NQ * 256;
    float* QB  = QA  + (size_t)NQ * 256;
    float* T1  = QB  + (size_t)NQ * 256;
    float* T2  = T1  + (size_t)NQ * 256;
    float* OFF = T2  + (size_t)NQ * 256;   // NQ*64
    float* AW  = OFF + (size_t)NQ * 64;    // NQ*32

    const dim3 blk(256);
    auto mmgrid = [](int M, int N) { return dim3((N + 63) / 64, M / 64); };

    // conv projections (A^T layout, B as (out,in)) then pre-attn linears
    mm64<true, true, false><<<mmgrid(NQ, 256), blk, 0, stream>>>(
        query, conv_q_w, conv_q_b, nullptr, T1, NQ, 256, CIN, NQ, CIN);
    mm64<false, false, false><<<mmgrid(NQ, 256), blk, 0, stream>>>(
        T1, lin_q_w, lin_q_b, nullptr, QA, NQ, 256, 256, 256, 256);
    mm64<true, true, false><<<mmgrid(NQ, 256), blk, 0, stream>>>(
        value, conv_v_w, conv_v_b, nullptr, T2, NQ, 256, CIN, NQ, CIN);
    mm64<false, false, false><<<mmgrid(NQ, 256), blk, 0, stream>>>(
        T2, lin_v_w, lin_v_b, nullptr, V, NQ, 256, 256, 256, 256);

    pos_kernel<<<NQ, 256, 0, stream>>>(row_embed, col_embed, POS);

    float* cur = QA;
    float* nxt = QB;
    for (int i = 0; i < 4; ++i) {
        // qp = cur + pos
        add_kernel<<<4096, 256, 0, stream>>>(cur, POS, T1, NQ * 64);
        const float* vin = (i < 3) ? V : cur;
        mm64<false, false, false><<<mmgrid(NQ, 256), blk, 0, stream>>>(
            vin, vp_w + (size_t)i * 256 * 256, vp_b + i * 256, nullptr, T2,
            NQ, 256, 256, 256, 256);
        mm64<false, false, false><<<mmgrid(NQ, 64), blk, 0, stream>>>(
            T1, off_w + (size_t)i * 256 * 64, off_b + i * 64, nullptr, OFF,
            NQ, 64, 256, 256, 64);
        mm64<false, false, false><<<mmgrid(NQ, 32), blk, 0, stream>>>(
            T1, aw_w + (size_t)i * 256 * 32, aw_b + i * 32, nullptr, AW,
            NQ, 32, 256, 256, 32);
        softmax4_kernel<<<512, 256, 0, stream>>>(AW, NQ * NH);
        sample_kernel<<<NQ, 256, 0, stream>>>(T2, OFF, AW, T1);
        mm64<false, false, false><<<mmgrid(NQ, 256), blk, 0, stream>>>(
            T1, op_w + (size_t)i * 256 * 256, op_b + i * 256, cur, nxt,
            NQ, 256, 256, 256, 256);
        float* tmp = cur; cur = nxt; nxt = tmp;
    }

    // output MLP
    mm64<false, false, false><<<mmgrid(NQ, 128), blk, 0, stream>>>(
        cur, out_w1, out_b1, nullptr, T1, NQ, 128, 256, 256, 128);
    ln_relu_kernel<128><<<4096, blk, 0, stream>>>(T1, ln1_g, ln1_b, NQ);
    mm64<false, false, false><<<mmgrid(NQ, 64), blk, 0, stream>>>(
        T1, out_w2, out_b2, nullptr, T2, NQ, 64, 128, 128, 64);
    ln_relu_kernel<64><<<4096, blk, 0, stream>>>(T2, ln2_g, ln2_b, NQ);
    mm64<false, false, true><<<mmgrid(NQ, CIN), blk, 0, stream>>>(
        T2, out_w3, out_b3, nullptr, (float*)d_out, NQ, CIN, 64, 64, CIN);
}

// Round 2
// 461.688 us; speedup vs baseline: 1.9854x; 1.9854x over previous
//
#include <hip/hip_runtime.h>
#include <hip/hip_bf16.h>

#define NQ   16384
#define DIM  256

using bf16 = __hip_bfloat16;
using bf16x8 = __attribute__((ext_vector_type(8))) short;
using f32x4  = __attribute__((ext_vector_type(4))) float;

__device__ __forceinline__ float b2f(bf16 x) { return __bfloat162float(x); }
__device__ __forceinline__ bf16  f2b(float x) { return __float2bfloat16(x); }
__device__ __forceinline__ unsigned short f2bb(float x) {
    bf16 h = __float2bfloat16(x);
    return *(unsigned short*)&h;
}

// ---------------------------------------------------------------------------
// MFMA bf16 GEMM: C[M,N] = A[M,K] @ B[N,K]^T + bias  (+ res)  (+ QP = C + pos)
// A: bf16 row-major [M][K]; B: bf16 prepacked [N][K]; bias fp32[N].
// BM = 32*MI, BN = 32*NI, BK = 64, 256 threads = 4 waves (2x2 wave grid).
// Requires: M % BM == 0, N % BN == 0, K % 64 == 0 (all true for this net).
// ---------------------------------------------------------------------------
template<int MI, int NI, bool RES, bool QP>
__global__ __launch_bounds__(256)
void gmm(const bf16* __restrict__ A, const bf16* __restrict__ B,
         const float* __restrict__ bias, const bf16* __restrict__ res,
         const bf16* __restrict__ pos, bf16* __restrict__ C, bf16* __restrict__ C2,
         int M, int N, int K)
{
    constexpr int BM = 32 * MI;
    constexpr int BN = 32 * NI;
    __shared__ bf16 As[BM][72];   // 64 + 8 pad: row stride 144B = 36 banks -> 2-way (free)
    __shared__ bf16 Bs[BN][72];

    const int t    = threadIdx.x;
    const int lane = t & 63;
    const int wid  = t >> 6;
    const int wm   = wid >> 1, wn = wid & 1;
    const int lr   = lane & 15;
    const int lg   = lane >> 4;

    const int m0 = blockIdx.y * BM;
    const int n0 = blockIdx.x * BN;

    f32x4 acc[MI][NI];
#pragma unroll
    for (int i = 0; i < MI; ++i)
#pragma unroll
        for (int j = 0; j < NI; ++j) {
            f32x4 z = {0.f, 0.f, 0.f, 0.f};
            acc[i][j] = z;
        }

    const bf16* Ab = A + (size_t)m0 * K;
    const bf16* Bb = B + (size_t)n0 * K;

    for (int k0 = 0; k0 < K; k0 += 64) {
#pragma unroll
        for (int c = 0; c < BM * 8; c += 256) {
            const int cc = c + t;
            const int row = cc >> 3, ks = cc & 7;
            *(int4*)&As[row][ks * 8] = *(const int4*)&Ab[(size_t)row * K + k0 + ks * 8];
        }
#pragma unroll
        for (int c = 0; c < BN * 8; c += 256) {
            const int cc = c + t;
            const int row = cc >> 3, ks = cc & 7;
            *(int4*)&Bs[row][ks * 8] = *(const int4*)&Bb[(size_t)row * K + k0 + ks * 8];
        }
        __syncthreads();
#pragma unroll
        for (int kk = 0; kk < 64; kk += 32) {
            bf16x8 af[MI], bv[NI];
            const int lk = kk + lg * 8;
#pragma unroll
            for (int i = 0; i < MI; ++i)
                af[i] = *(const bf16x8*)&As[wm * (MI * 16) + i * 16 + lr][lk];
#pragma unroll
            for (int j = 0; j < NI; ++j)
                bv[j] = *(const bf16x8*)&Bs[wn * (NI * 16) + j * 16 + lr][lk];
#pragma unroll
            for (int i = 0; i < MI; ++i)
#pragma unroll
                for (int j = 0; j < NI; ++j)
                    acc[i][j] = __builtin_amdgcn_mfma_f32_16x16x32_bf16(
                        af[i], bv[j], acc[i][j], 0, 0, 0);
        }
        __syncthreads();
    }

    // epilogue: C/D layout col = lane&15, row = (lane>>4)*4 + reg
#pragma unroll
    for (int i = 0; i < MI; ++i) {
#pragma unroll
        for (int j = 0; j < NI; ++j) {
            const int row0 = m0 + wm * (MI * 16) + i * 16 + lg * 4;
            const int col  = n0 + wn * (NI * 16) + j * 16 + lr;
            const float bvl = bias[col];
#pragma unroll
            for (int r = 0; r < 4; ++r) {
                const size_t off = (size_t)(row0 + r) * N + col;
                float v = acc[i][j][r] + bvl;
                if (RES) v += b2f(res[off]);
                C[off] = f2b(v);
                if (QP) {
                    const size_t poff = (size_t)(row0 + r) * 256 + col;
                    C2[poff] = f2b(v + b2f(pos[poff]));
                }
            }
        }
    }
}

// fp32 [C=384][M=16384] -> bf16 [M][384]   (64x64 LDS tile transpose)
__global__ __launch_bounds__(256)
void transpose_in(const float* __restrict__ in, bf16* __restrict__ out)
{
    __shared__ float tile[64][68];
    const int t = threadIdx.x;
    const int c0 = blockIdx.x * 64, m0 = blockIdx.y * 64;
    const int tr = t >> 4;
    const int tc4 = (t & 15) * 4;
#pragma unroll
    for (int i = 0; i < 4; ++i) {
        const int c = i * 16 + tr;
        const float4 v = *(const float4*)&in[(size_t)(c0 + c) * NQ + m0 + tc4];
        tile[tc4 + 0][c] = v.x; tile[tc4 + 1][c] = v.y;
        tile[tc4 + 2][c] = v.z; tile[tc4 + 3][c] = v.w;
    }
    __syncthreads();
#pragma unroll
    for (int i = 0; i < 4; ++i) {
        const int m = i * 16 + tr;
        ushort4 o;
        o.x = f2bb(tile[m][tc4 + 0]); o.y = f2bb(tile[m][tc4 + 1]);
        o.z = f2bb(tile[m][tc4 + 2]); o.w = f2bb(tile[m][tc4 + 3]);
        *(ushort4*)&out[(size_t)(m0 + m) * 384 + c0 + tc4] = o;
    }
}

// bf16 [M=16384][384] -> fp32 [384][M]   (final output transpose)
__global__ __launch_bounds__(256)
void transpose_out(const bf16* __restrict__ in, float* __restrict__ out)
{
    __shared__ float tile[64][68];
    const int t = threadIdx.x;
    const int c0 = blockIdx.x * 64, m0 = blockIdx.y * 64;
    const int tr = t >> 4;
    const int tc4 = (t & 15) * 4;
#pragma unroll
    for (int i = 0; i < 4; ++i) {
        const int m = i * 16 + tr;
        const ushort4 v = *(const ushort4*)&in[(size_t)(m0 + m) * 384 + c0 + tc4];
        tile[tc4 + 0][m] = b2f(*(bf16*)&v.x);
        tile[tc4 + 1][m] = b2f(*(bf16*)&v.y);
        tile[tc4 + 2][m] = b2f(*(bf16*)&v.z);
        tile[tc4 + 3][m] = b2f(*(bf16*)&v.w);
    }
    __syncthreads();
#pragma unroll
    for (int i = 0; i < 4; ++i) {
        const int c = i * 16 + tr;
        float4 o;
        o.x = tile[c][tc4 + 0]; o.y = tile[c][tc4 + 1];
        o.z = tile[c][tc4 + 2]; o.w = tile[c][tc4 + 3];
        *(float4*)&out[(size_t)(c0 + c) * NQ + m0 + tc4] = o;
    }
}

// all small weight transposes fp32 [K][N] -> bf16 [N][K], + oa-bias concat
__global__ __launch_bounds__(256)
void prep_weights(const float* __restrict__ vp_w, const float* __restrict__ op_w,
                  const float* __restrict__ off_w, const float* __restrict__ aw_w,
                  const float* __restrict__ off_b, const float* __restrict__ aw_b,
                  const float* __restrict__ w1, const float* __restrict__ w2,
                  const float* __restrict__ w3,
                  bf16* __restrict__ WVP, bf16* __restrict__ WOP, bf16* __restrict__ WOA,
                  bf16* __restrict__ WM1, bf16* __restrict__ WM2, bf16* __restrict__ WM3,
                  float* __restrict__ OAB)
{
    int idx = blockIdx.x * 256 + threadIdx.x;
    auto tr = [](const float* src, bf16* dst, int K, int N, int i) {
        const int n = i / K, k = i % K;
        dst[i] = __float2bfloat16(src[k * N + n]);
    };
    if (idx < 262144) { const int l = idx >> 16, r = idx & 65535; tr(vp_w + l * 65536, WVP + l * 65536, 256, 256, r); return; }
    idx -= 262144;
    if (idx < 262144) { const int l = idx >> 16, r = idx & 65535; tr(op_w + l * 65536, WOP + l * 65536, 256, 256, r); return; }
    idx -= 262144;
    if (idx < 65536) { const int l = idx >> 14, r = idx & 16383; tr(off_w + l * 16384, WOA + l * 24576, 256, 64, r); return; }
    idx -= 65536;
    if (idx < 32768) { const int l = idx >> 13, r = idx & 8191; tr(aw_w + l * 8192, WOA + l * 24576 + 64 * 256, 256, 32, r); return; }
    idx -= 32768;
    if (idx < 32768) { tr(w1, WM1, 256, 128, idx); return; }
    idx -= 32768;
    if (idx < 8192) { tr(w2, WM2, 128, 64, idx); return; }
    idx -= 8192;
    if (idx < 24576) { tr(w3, WM3, 64, 384, idx); return; }
    idx -= 24576;
    if (idx < 384) {
        const int l = idx / 96, r = idx % 96;
        OAB[idx] = (r < 64) ? off_b[l * 64 + r] : aw_b[l * 32 + r - 64];
    }
}

// combined conv1x1+linear weights: W'[n][c] = sum_d conv_w[d][c] * lin_w[d][n]
__global__ __launch_bounds__(256)
void prep_combined(const float* __restrict__ cqw, const float* __restrict__ cqb,
                   const float* __restrict__ cvw, const float* __restrict__ cvb,
                   const float* __restrict__ lqw, const float* __restrict__ lqb,
                   const float* __restrict__ lvw, const float* __restrict__ lvb,
                   bf16* __restrict__ WQ, bf16* __restrict__ WV,
                   float* __restrict__ BQ, float* __restrict__ BV)
{
    const int b = blockIdx.x;
    if (b < 768) {
        const bool isq = b < 384;
        const float* cw = isq ? cqw : cvw;
        const float* lw = isq ? lqw : lvw;
        bf16* W = isq ? WQ : WV;
        const int idx = (b % 384) * 256 + threadIdx.x;   // idx = n*384 + c
        const int n = idx / 384, c = idx % 384;
        float s = 0.f;
        for (int d = 0; d < 256; ++d)
            s = fmaf(cw[d * 384 + c], lw[d * 256 + n], s);
        W[idx] = f2b(s);
    } else {
        const int n = threadIdx.x;
        float sq = lqb[n], sv = lvb[n];
        for (int d = 0; d < 256; ++d) {
            sq = fmaf(cqb[d], lqw[d * 256 + n], sq);
            sv = fmaf(cvb[d], lvw[d * 256 + n], sv);
        }
        BQ[n] = sq; BV[n] = sv;
    }
}

__global__ __launch_bounds__(256)
void pos_kernel(const float* __restrict__ row_embed, const float* __restrict__ col_embed,
                bf16* __restrict__ pos)
{
    const int idx = blockIdx.x * 256 + threadIdx.x;
    const int pix = idx >> 8, d = idx & 255;
    const int h = pix >> 7, w = pix & 127;
    pos[idx] = f2b((d < 128) ? col_embed[w * 128 + d] : row_embed[h * 128 + (d - 128)]);
}

__device__ __forceinline__ float fetch_val(const bf16* __restrict__ val, int y, int x, int d)
{
    if ((unsigned)y < 128u && (unsigned)x < 128u)
        return b2f(val[(size_t)((y << 7) + x) * DIM + d]);
    return 0.f;
}

// fused softmax(aw) + bilinear deform sampling; one block per pixel
__global__ __launch_bounds__(256)
void sample_kernel(const bf16* __restrict__ val, const bf16* __restrict__ oa,
                   bf16* __restrict__ out)
{
    const int pix = blockIdx.x;
    const int d = threadIdx.x;
    const int head = d >> 5;
    const float fx = (float)(pix & 127);
    const float fy = (float)(pix >> 7);
    const bf16* oap = oa + (size_t)pix * 96;
    float lgt[4];
    float mx = -1e30f;
#pragma unroll
    for (int p = 0; p < 4; ++p) {
        lgt[p] = b2f(oap[64 + head * 4 + p]);
        mx = fmaxf(mx, lgt[p]);
    }
    float e[4], ssum = 0.f;
#pragma unroll
    for (int p = 0; p < 4; ++p) { e[p] = __expf(lgt[p] - mx); ssum += e[p]; }
    const float inv = 1.f / ssum;
    float accv = 0.f;
#pragma unroll
    for (int p = 0; p < 4; ++p) {
        const float x = fx + b2f(oap[head * 8 + p * 2 + 0]);
        const float y = fy + b2f(oap[head * 8 + p * 2 + 1]);
        const float a = e[p] * inv;
        const float x0f = floorf(x), y0f = floorf(y);
        const float lx = x - x0f, ly = y - y0f;
        const int x0 = (int)x0f, y0 = (int)y0f;
        accv = fmaf(fetch_val(val, y0,     x0,     d), (1.f - lx) * (1.f - ly) * a, accv);
        accv = fmaf(fetch_val(val, y0,     x0 + 1, d), lx * (1.f - ly) * a, accv);
        accv = fmaf(fetch_val(val, y0 + 1, x0,     d), (1.f - lx) * ly * a, accv);
        accv = fmaf(fetch_val(val, y0 + 1, x0 + 1, d), lx * ly * a, accv);
    }
    out[(size_t)pix * DIM + d] = f2b(accv);
}

// in-place LayerNorm + ReLU over rows of width C, fp32 math, 1 wave per row
template<int C>
__global__ __launch_bounds__(256)
void ln_relu(bf16* __restrict__ x, const float* __restrict__ g, const float* __restrict__ b)
{
    const int row = blockIdx.x * 4 + (threadIdx.x >> 6);
    const int lane = threadIdx.x & 63;
    bf16* xp = x + (size_t)row * C;
    const float v0 = b2f(xp[lane]);
    const float v1 = (C > 64) ? b2f(xp[lane + 64]) : 0.f;
    float s = v0 + v1;
#pragma unroll
    for (int o = 32; o; o >>= 1) s += __shfl_xor(s, o);
    const float mu = s / (float)C;
    const float d0 = v0 - mu;
    const float d1 = (C > 64) ? (v1 - mu) : 0.f;
    float vs = d0 * d0 + d1 * d1;
#pragma unroll
    for (int o = 32; o; o >>= 1) vs += __shfl_xor(vs, o);
    const float rstd = rsqrtf(vs / (float)C + 1e-5f);
    xp[lane] = f2b(fmaxf(d0 * rstd * g[lane] + b[lane], 0.f));
    if (C > 64)
        xp[lane + 64] = f2b(fmaxf(d1 * rstd * g[lane + 64] + b[lane + 64], 0.f));
}

extern "C" void kernel_launch(void* const* d_in, const int* in_sizes, int n_in,
                              void* d_out, int out_size, void* d_ws, size_t ws_size,
                              hipStream_t stream)
{
    const float* query     = (const float*)d_in[0];
    const float* value     = (const float*)d_in[1];
    const float* conv_q_w  = (const float*)d_in[2];
    const float* conv_q_b  = (const float*)d_in[3];
    const float* conv_v_w  = (const float*)d_in[4];
    const float* conv_v_b  = (const float*)d_in[5];
    const float* row_embed = (const float*)d_in[6];
    const float* col_embed = (const float*)d_in[7];
    const float* lin_q_w   = (const float*)d_in[8];
    const float* lin_q_b   = (const float*)d_in[9];
    const float* lin_v_w   = (const float*)d_in[10];
    const float* lin_v_b   = (const float*)d_in[11];
    const float* off_w     = (const float*)d_in[12];
    const float* off_b     = (const float*)d_in[13];
    const float* aw_w      = (const float*)d_in[14];
    const float* aw_b      = (const float*)d_in[15];
    const float* vp_w      = (const float*)d_in[16];
    const float* vp_b      = (const float*)d_in[17];
    const float* op_w      = (const float*)d_in[18];
    const float* op_b      = (const float*)d_in[19];
    const float* out_w1    = (const float*)d_in[20];
    const float* out_b1    = (const float*)d_in[21];
    const float* ln1_g     = (const float*)d_in[22];
    const float* ln1_b     = (const float*)d_in[23];
    const float* out_w2    = (const float*)d_in[24];
    const float* out_b2    = (const float*)d_in[25];
    const float* ln2_g     = (const float*)d_in[26];
    const float* ln2_b     = (const float*)d_in[27];
    const float* out_w3    = (const float*)d_in[28];
    const float* out_b3    = (const float*)d_in[29];

    bf16* w = (bf16*)d_ws;
    auto alloc = [&](size_t n) { bf16* p = w; w += n; return p; };
    bf16* QT  = alloc((size_t)NQ * 384);
    bf16* VT  = alloc((size_t)NQ * 384);
    bf16* POS = alloc((size_t)NQ * 256);
    bf16* QA  = alloc((size_t)NQ * 256);
    bf16* QB  = alloc((size_t)NQ * 256);
    bf16* QPb = alloc((size_t)NQ * 256);
    bf16* V   = alloc((size_t)NQ * 256);
    bf16* T1  = alloc((size_t)NQ * 256);
    bf16* T2  = alloc((size_t)NQ * 256);
    bf16* OA  = alloc((size_t)NQ * 96);
    bf16* WQc = alloc(256 * 384);
    bf16* WVc = alloc(256 * 384);
    bf16* WVP = alloc(4 * 256 * 256);
    bf16* WOP = alloc(4 * 256 * 256);
    bf16* WOA = alloc(4 * 96 * 256);
    bf16* WM1 = alloc(128 * 256);
    bf16* WM2 = alloc(64 * 128);
    bf16* WM3 = alloc(384 * 64);
    float* fp = (float*)w;
    float* BQc = fp; fp += 256;
    float* BVc = fp; fp += 256;
    float* OAB = fp; fp += 384;

    const dim3 blk(256);

    transpose_in<<<dim3(6, 256), blk, 0, stream>>>(query, QT);
    transpose_in<<<dim3(6, 256), blk, 0, stream>>>(value, VT);
    prep_weights<<<2690, blk, 0, stream>>>(vp_w, op_w, off_w, aw_w, off_b, aw_b,
                                           out_w1, out_w2, out_w3,
                                           WVP, WOP, WOA, WM1, WM2, WM3, OAB);
    prep_combined<<<769, blk, 0, stream>>>(conv_q_w, conv_q_b, conv_v_w, conv_v_b,
                                           lin_q_w, lin_q_b, lin_v_w, lin_v_b,
                                           WQc, WVc, BQc, BVc);
    pos_kernel<<<16384, blk, 0, stream>>>(row_embed, col_embed, POS);

    // q = QT @ WQc^T + BQc; QP = q + pos     | v = VT @ WVc^T + BVc
    gmm<2, 4, false, true><<<dim3(2, 256), blk, 0, stream>>>(
        QT, WQc, BQc, nullptr, POS, QA, QPb, NQ, 256, 384);
    gmm<2, 4, false, false><<<dim3(2, 256), blk, 0, stream>>>(
        VT, WVc, BVc, nullptr, nullptr, V, nullptr, NQ, 256, 384);

    bf16* cur = QA;
    bf16* nxt = QB;
    for (int i = 0; i < 4; ++i) {
        const bf16* vin = (i < 3) ? V : cur;
        gmm<2, 4, false, false><<<dim3(2, 256), blk, 0, stream>>>(
            vin, WVP + (size_t)i * 65536, vp_b + i * 256, nullptr, nullptr,
            T2, nullptr, NQ, 256, 256);
        gmm<2, 3, false, false><<<dim3(1, 256), blk, 0, stream>>>(
            QPb, WOA + (size_t)i * 24576, OAB + i * 96, nullptr, nullptr,
            OA, nullptr, NQ, 96, 256);
        sample_kernel<<<16384, blk, 0, stream>>>(T2, OA, T1);
        gmm<2, 4, true, true><<<dim3(2, 256), blk, 0, stream>>>(
            T1, WOP + (size_t)i * 65536, op_b + i * 256, cur, POS,
            nxt, QPb, NQ, 256, 256);
        bf16* tmp = cur; cur = nxt; nxt = tmp;
    }

    // output MLP
    gmm<2, 4, false, false><<<dim3(1, 256), blk, 0, stream>>>(
        cur, WM1, out_b1, nullptr, nullptr, T1, nullptr, NQ, 128, 256);
    ln_relu<128><<<4096, blk, 0, stream>>>(T1, ln1_g, ln1_b);
    gmm<2, 2, false, false><<<dim3(1, 256), blk, 0, stream>>>(
        T1, WM2, out_b2, nullptr, nullptr, T2, nullptr, NQ, 64, 128);
    ln_relu<64><<<4096, blk, 0, stream>>>(T2, ln2_g, ln2_b);
    gmm<2, 4, false, false><<<dim3(3, 256), blk, 0, stream>>>(
        T2, WM3, out_b3, nullptr, nullptr, QT, nullptr, NQ, 384, 64);
    transpose_out<<<dim3(6, 256), blk, 0, stream>>>(QT, (float*)d_out);
}

// Round 3
// 277.939 us; speedup vs baseline: 3.2980x; 1.6611x over previous
//
#include <hip/hip_runtime.h>
#include <hip/hip_bf16.h>

#define NQ   16384
#define DIM  256

using bf16 = __hip_bfloat16;
using bf16x8 = __attribute__((ext_vector_type(8))) short;
using f32x4  = __attribute__((ext_vector_type(4))) float;

__device__ __forceinline__ float b2f(bf16 x) { return __bfloat162float(x); }
__device__ __forceinline__ bf16  f2b(float x) { return __float2bfloat16(x); }
__device__ __forceinline__ unsigned short f2bb(float x) {
    bf16 h = __float2bfloat16(x);
    return *(unsigned short*)&h;
}
__device__ __forceinline__ float us2f(unsigned short u) {
    unsigned int x = ((unsigned int)u) << 16;
    return __builtin_bit_cast(float, x);
}

// ---------------------------------------------------------------------------
// MFMA bf16 GEMM: C[M,N] = A[M,K] @ B[N,K]^T + bias  (+ res)  (+ QP = C + pos)
// A: bf16 row-major [M][K]; B: bf16 prepacked [N][K]; bias fp32[N].
// BM = 32*MI, BN = 32*NI, BK = 64, 256 threads = 4 waves (2x2 wave grid).
// Requires: M % BM == 0, N % BN == 0, K % 64 == 0 (all true for this net).
// ---------------------------------------------------------------------------
template<int MI, int NI, bool RES, bool QP>
__global__ __launch_bounds__(256)
void gmm(const bf16* __restrict__ A, const bf16* __restrict__ B,
         const float* __restrict__ bias, const bf16* __restrict__ res,
         const bf16* __restrict__ pos, bf16* __restrict__ C, bf16* __restrict__ C2,
         int M, int N, int K)
{
    constexpr int BM = 32 * MI;
    constexpr int BN = 32 * NI;
    __shared__ bf16 As[BM][72];   // 64 + 8 pad: 144B row stride -> 2-way conflicts only
    __shared__ bf16 Bs[BN][72];

    const int t    = threadIdx.x;
    const int lane = t & 63;
    const int wid  = t >> 6;
    const int wm   = wid >> 1, wn = wid & 1;
    const int lr   = lane & 15;
    const int lg   = lane >> 4;

    const int m0 = blockIdx.y * BM;
    const int n0 = blockIdx.x * BN;

    f32x4 acc[MI][NI];
#pragma unroll
    for (int i = 0; i < MI; ++i)
#pragma unroll
        for (int j = 0; j < NI; ++j) {
            f32x4 z = {0.f, 0.f, 0.f, 0.f};
            acc[i][j] = z;
        }

    const bf16* Ab = A + (size_t)m0 * K;
    const bf16* Bb = B + (size_t)n0 * K;

    for (int k0 = 0; k0 < K; k0 += 64) {
#pragma unroll
        for (int c = 0; c < BM * 8; c += 256) {
            const int cc = c + t;
            const int row = cc >> 3, ks = cc & 7;
            *(int4*)&As[row][ks * 8] = *(const int4*)&Ab[(size_t)row * K + k0 + ks * 8];
        }
#pragma unroll
        for (int c = 0; c < BN * 8; c += 256) {
            const int cc = c + t;
            const int row = cc >> 3, ks = cc & 7;
            *(int4*)&Bs[row][ks * 8] = *(const int4*)&Bb[(size_t)row * K + k0 + ks * 8];
        }
        __syncthreads();
#pragma unroll
        for (int kk = 0; kk < 64; kk += 32) {
            bf16x8 af[MI], bv[NI];
            const int lk = kk + lg * 8;
#pragma unroll
            for (int i = 0; i < MI; ++i)
                af[i] = *(const bf16x8*)&As[wm * (MI * 16) + i * 16 + lr][lk];
#pragma unroll
            for (int j = 0; j < NI; ++j)
                bv[j] = *(const bf16x8*)&Bs[wn * (NI * 16) + j * 16 + lr][lk];
#pragma unroll
            for (int i = 0; i < MI; ++i)
#pragma unroll
                for (int j = 0; j < NI; ++j)
                    acc[i][j] = __builtin_amdgcn_mfma_f32_16x16x32_bf16(
                        af[i], bv[j], acc[i][j], 0, 0, 0);
        }
        __syncthreads();
    }

    // epilogue: C/D layout col = lane&15, row = (lane>>4)*4 + reg
#pragma unroll
    for (int i = 0; i < MI; ++i) {
#pragma unroll
        for (int j = 0; j < NI; ++j) {
            const int row0 = m0 + wm * (MI * 16) + i * 16 + lg * 4;
            const int col  = n0 + wn * (NI * 16) + j * 16 + lr;
            const float bvl = bias[col];
#pragma unroll
            for (int r = 0; r < 4; ++r) {
                const size_t off = (size_t)(row0 + r) * N + col;
                float v = acc[i][j][r] + bvl;
                if (RES) v += b2f(res[off]);
                C[off] = f2b(v);
                if (QP) {
                    const size_t poff = (size_t)(row0 + r) * 256 + col;
                    C2[poff] = f2b(v + b2f(pos[poff]));
                }
            }
        }
    }
}

// fp32 [C=384][M=16384] -> bf16 [M][384]   (64x64 LDS tile transpose)
__global__ __launch_bounds__(256)
void transpose_in(const float* __restrict__ in, bf16* __restrict__ out)
{
    __shared__ float tile[64][68];
    const int t = threadIdx.x;
    const int c0 = blockIdx.x * 64, m0 = blockIdx.y * 64;
    const int tr = t >> 4;
    const int tc4 = (t & 15) * 4;
#pragma unroll
    for (int i = 0; i < 4; ++i) {
        const int c = i * 16 + tr;
        const float4 v = *(const float4*)&in[(size_t)(c0 + c) * NQ + m0 + tc4];
        tile[tc4 + 0][c] = v.x; tile[tc4 + 1][c] = v.y;
        tile[tc4 + 2][c] = v.z; tile[tc4 + 3][c] = v.w;
    }
    __syncthreads();
#pragma unroll
    for (int i = 0; i < 4; ++i) {
        const int m = i * 16 + tr;
        ushort4 o;
        o.x = f2bb(tile[m][tc4 + 0]); o.y = f2bb(tile[m][tc4 + 1]);
        o.z = f2bb(tile[m][tc4 + 2]); o.w = f2bb(tile[m][tc4 + 3]);
        *(ushort4*)&out[(size_t)(m0 + m) * 384 + c0 + tc4] = o;
    }
}

// bf16 [M=16384][384] -> fp32 [384][M]   (final output transpose)
__global__ __launch_bounds__(256)
void transpose_out(const bf16* __restrict__ in, float* __restrict__ out)
{
    __shared__ float tile[64][68];
    const int t = threadIdx.x;
    const int c0 = blockIdx.x * 64, m0 = blockIdx.y * 64;
    const int tr = t >> 4;
    const int tc4 = (t & 15) * 4;
#pragma unroll
    for (int i = 0; i < 4; ++i) {
        const int m = i * 16 + tr;
        const ushort4 v = *(const ushort4*)&in[(size_t)(m0 + m) * 384 + c0 + tc4];
        tile[tc4 + 0][m] = us2f(v.x);
        tile[tc4 + 1][m] = us2f(v.y);
        tile[tc4 + 2][m] = us2f(v.z);
        tile[tc4 + 3][m] = us2f(v.w);
    }
    __syncthreads();
#pragma unroll
    for (int i = 0; i < 4; ++i) {
        const int c = i * 16 + tr;
        float4 o;
        o.x = tile[c][tc4 + 0]; o.y = tile[c][tc4 + 1];
        o.z = tile[c][tc4 + 2]; o.w = tile[c][tc4 + 3];
        *(float4*)&out[(size_t)(c0 + c) * NQ + m0 + tc4] = o;
    }
}

// all small weight transposes fp32 [K][N] -> bf16 [N][K], + oa-bias concat
__global__ __launch_bounds__(256)
void prep_weights(const float* __restrict__ vp_w, const float* __restrict__ op_w,
                  const float* __restrict__ off_w, const float* __restrict__ aw_w,
                  const float* __restrict__ off_b, const float* __restrict__ aw_b,
                  const float* __restrict__ w1, const float* __restrict__ w2,
                  const float* __restrict__ w3,
                  bf16* __restrict__ WVP, bf16* __restrict__ WOP, bf16* __restrict__ WOA,
                  bf16* __restrict__ WM1, bf16* __restrict__ WM2, bf16* __restrict__ WM3,
                  float* __restrict__ OAB)
{
    int idx = blockIdx.x * 256 + threadIdx.x;
    auto tr = [](const float* src, bf16* dst, int K, int N, int i) {
        const int n = i / K, k = i % K;
        dst[i] = __float2bfloat16(src[k * N + n]);
    };
    if (idx < 262144) { const int l = idx >> 16, r = idx & 65535; tr(vp_w + l * 65536, WVP + l * 65536, 256, 256, r); return; }
    idx -= 262144;
    if (idx < 262144) { const int l = idx >> 16, r = idx & 65535; tr(op_w + l * 65536, WOP + l * 65536, 256, 256, r); return; }
    idx -= 262144;
    if (idx < 65536) { const int l = idx >> 14, r = idx & 16383; tr(off_w + l * 16384, WOA + l * 24576, 256, 64, r); return; }
    idx -= 65536;
    if (idx < 32768) { const int l = idx >> 13, r = idx & 8191; tr(aw_w + l * 8192, WOA + l * 24576 + 64 * 256, 256, 32, r); return; }
    idx -= 32768;
    if (idx < 32768) { tr(w1, WM1, 256, 128, idx); return; }
    idx -= 32768;
    if (idx < 8192) { tr(w2, WM2, 128, 64, idx); return; }
    idx -= 8192;
    if (idx < 24576) { tr(w3, WM3, 64, 384, idx); return; }
    idx -= 24576;
    if (idx < 384) {
        const int l = idx / 96, r = idx % 96;
        OAB[idx] = (r < 64) ? off_b[l * 64 + r] : aw_b[l * 32 + r - 64];
    }
}

// combined conv1x1+linear weights: W'[n][c] = sum_d conv_w[d][c] * lin_w[d][n]
__global__ __launch_bounds__(256)
void prep_combined(const float* __restrict__ cqw, const float* __restrict__ cqb,
                   const float* __restrict__ cvw, const float* __restrict__ cvb,
                   const float* __restrict__ lqw, const float* __restrict__ lqb,
                   const float* __restrict__ lvw, const float* __restrict__ lvb,
                   bf16* __restrict__ WQ, bf16* __restrict__ WV,
                   float* __restrict__ BQ, float* __restrict__ BV)
{
    const int b = blockIdx.x;
    if (b < 768) {
        const bool isq = b < 384;
        const float* cw = isq ? cqw : cvw;
        const float* lw = isq ? lqw : lvw;
        bf16* W = isq ? WQ : WV;
        const int idx = (b % 384) * 256 + threadIdx.x;   // idx = n*384 + c
        const int n = idx / 384, c = idx % 384;
        float s = 0.f;
        for (int d = 0; d < 256; ++d)
            s = fmaf(cw[d * 384 + c], lw[d * 256 + n], s);
        W[idx] = f2b(s);
    } else {
        const int n = threadIdx.x;
        float sq = lqb[n], sv = lvb[n];
        for (int d = 0; d < 256; ++d) {
            sq = fmaf(cqb[d], lqw[d * 256 + n], sq);
            sv = fmaf(cvb[d], lvw[d * 256 + n], sv);
        }
        BQ[n] = sq; BV[n] = sv;
    }
}

__global__ __launch_bounds__(256)
void pos_kernel(const float* __restrict__ row_embed, const float* __restrict__ col_embed,
                bf16* __restrict__ pos)
{
    const int idx = blockIdx.x * 256 + threadIdx.x;
    const int pix = idx >> 8, d = idx & 255;
    const int h = pix >> 7, w = pix & 127;
    pos[idx] = f2b((d < 128) ? col_embed[w * 128 + d] : row_embed[h * 128 + (d - 128)]);
}

// fused softmax + bilinear deform sampling.
// 32 threads per pixel, 8 channels per thread (all loads are 16B bf16x8).
// 8 pixels per 256-thread block.
__global__ __launch_bounds__(256)
void sample_kernel(const bf16* __restrict__ val, const bf16* __restrict__ oa,
                   bf16* __restrict__ out)
{
    const int tid = threadIdx.x;
    const int pix = blockIdx.x * 8 + (tid >> 5);
    const int thr = tid & 31;
    const int head = thr >> 2;
    const int c0 = thr * 8;
    const float fx = (float)(pix & 127);
    const float fy = (float)(pix >> 7);
    const unsigned short* oap = (const unsigned short*)(oa + (size_t)pix * 96);
    const bf16x8 offs = *(const bf16x8*)&oap[head * 8];
    const ushort4 lg4 = *(const ushort4*)&oap[64 + head * 4];
    const float l0 = us2f(lg4.x), l1 = us2f(lg4.y), l2 = us2f(lg4.z), l3 = us2f(lg4.w);
    const float mx = fmaxf(fmaxf(l0, l1), fmaxf(l2, l3));
    const float e0 = __expf(l0 - mx), e1 = __expf(l1 - mx);
    const float e2 = __expf(l2 - mx), e3 = __expf(l3 - mx);
    const float inv = 1.f / (e0 + e1 + e2 + e3);
    const float aw4[4] = {e0 * inv, e1 * inv, e2 * inv, e3 * inv};

    float acc[8];
#pragma unroll
    for (int c = 0; c < 8; ++c) acc[c] = 0.f;

#pragma unroll
    for (int p = 0; p < 4; ++p) {
        const float x = fx + us2f((unsigned short)offs[p * 2 + 0]);
        const float y = fy + us2f((unsigned short)offs[p * 2 + 1]);
        const float x0f = floorf(x), y0f = floorf(y);
        const float lx = x - x0f, ly = y - y0f;
        const int x0 = (int)x0f, y0 = (int)y0f;
        const float a = aw4[p];
        const float wc[4] = {(1.f - lx) * (1.f - ly) * a, lx * (1.f - ly) * a,
                             (1.f - lx) * ly * a,         lx * ly * a};
        const int xs[4] = {x0, x0 + 1, x0, x0 + 1};
        const int ys[4] = {y0, y0, y0 + 1, y0 + 1};
#pragma unroll
        for (int k = 0; k < 4; ++k) {
            if ((unsigned)ys[k] < 128u && (unsigned)xs[k] < 128u) {
                const bf16x8 v = *(const bf16x8*)&val[(size_t)((ys[k] << 7) + xs[k]) * 256 + c0];
                const float w = wc[k];
#pragma unroll
                for (int c = 0; c < 8; ++c)
                    acc[c] = fmaf(us2f((unsigned short)v[c]), w, acc[c]);
            }
        }
    }
    bf16x8 o;
#pragma unroll
    for (int c = 0; c < 8; ++c) o[c] = (short)f2bb(acc[c]);
    *(bf16x8*)&out[(size_t)pix * 256 + c0] = o;
}

// in-place LayerNorm + ReLU over rows of width C, fp32 math, 1 wave per row
template<int C>
__global__ __launch_bounds__(256)
void ln_relu(bf16* __restrict__ x, const float* __restrict__ g, const float* __restrict__ b)
{
    const int row = blockIdx.x * 4 + (threadIdx.x >> 6);
    const int lane = threadIdx.x & 63;
    bf16* xp = x + (size_t)row * C;
    const float v0 = b2f(xp[lane]);
    const float v1 = (C > 64) ? b2f(xp[lane + 64]) : 0.f;
    float s = v0 + v1;
#pragma unroll
    for (int o = 32; o; o >>= 1) s += __shfl_xor(s, o);
    const float mu = s / (float)C;
    const float d0 = v0 - mu;
    const float d1 = (C > 64) ? (v1 - mu) : 0.f;
    float vs = d0 * d0 + d1 * d1;
#pragma unroll
    for (int o = 32; o; o >>= 1) vs += __shfl_xor(vs, o);
    const float rstd = rsqrtf(vs / (float)C + 1e-5f);
    xp[lane] = f2b(fmaxf(d0 * rstd * g[lane] + b[lane], 0.f));
    if (C > 64)
        xp[lane + 64] = f2b(fmaxf(d1 * rstd * g[lane + 64] + b[lane + 64], 0.f));
}

extern "C" void kernel_launch(void* const* d_in, const int* in_sizes, int n_in,
                              void* d_out, int out_size, void* d_ws, size_t ws_size,
                              hipStream_t stream)
{
    const float* query     = (const float*)d_in[0];
    const float* value     = (const float*)d_in[1];
    const float* conv_q_w  = (const float*)d_in[2];
    const float* conv_q_b  = (const float*)d_in[3];
    const float* conv_v_w  = (const float*)d_in[4];
    const float* conv_v_b  = (const float*)d_in[5];
    const float* row_embed = (const float*)d_in[6];
    const float* col_embed = (const float*)d_in[7];
    const float* lin_q_w   = (const float*)d_in[8];
    const float* lin_q_b   = (const float*)d_in[9];
    const float* lin_v_w   = (const float*)d_in[10];
    const float* lin_v_b   = (const float*)d_in[11];
    const float* off_w     = (const float*)d_in[12];
    const float* off_b     = (const float*)d_in[13];
    const float* aw_w      = (const float*)d_in[14];
    const float* aw_b      = (const float*)d_in[15];
    const float* vp_w      = (const float*)d_in[16];
    const float* vp_b      = (const float*)d_in[17];
    const float* op_w      = (const float*)d_in[18];
    const float* op_b      = (const float*)d_in[19];
    const float* out_w1    = (const float*)d_in[20];
    const float* out_b1    = (const float*)d_in[21];
    const float* ln1_g     = (const float*)d_in[22];
    const float* ln1_b     = (const float*)d_in[23];
    const float* out_w2    = (const float*)d_in[24];
    const float* out_b2    = (const float*)d_in[25];
    const float* ln2_g     = (const float*)d_in[26];
    const float* ln2_b     = (const float*)d_in[27];
    const float* out_w3    = (const float*)d_in[28];
    const float* out_b3    = (const float*)d_in[29];

    bf16* w = (bf16*)d_ws;
    auto alloc = [&](size_t n) { bf16* p = w; w += n; return p; };
    bf16* QT  = alloc((size_t)NQ * 384);
    bf16* VT  = alloc((size_t)NQ * 384);
    bf16* POS = alloc((size_t)NQ * 256);
    bf16* QA  = alloc((size_t)NQ * 256);
    bf16* QB  = alloc((size_t)NQ * 256);
    bf16* QPb = alloc((size_t)NQ * 256);
    bf16* V   = alloc((size_t)NQ * 256);
    bf16* T1  = alloc((size_t)NQ * 256);
    bf16* T2  = alloc((size_t)NQ * 256);
    bf16* OA  = alloc((size_t)NQ * 96);
    bf16* WQc = alloc(256 * 384);
    bf16* WVc = alloc(256 * 384);
    bf16* WVP = alloc(4 * 256 * 256);
    bf16* WOP = alloc(4 * 256 * 256);
    bf16* WOA = alloc(4 * 96 * 256);
    bf16* WM1 = alloc(128 * 256);
    bf16* WM2 = alloc(64 * 128);
    bf16* WM3 = alloc(384 * 64);
    float* fp = (float*)w;
    float* BQc = fp; fp += 256;
    float* BVc = fp; fp += 256;
    float* OAB = fp; fp += 384;

    const dim3 blk(256);

    transpose_in<<<dim3(6, 256), blk, 0, stream>>>(query, QT);
    transpose_in<<<dim3(6, 256), blk, 0, stream>>>(value, VT);
    prep_weights<<<2690, blk, 0, stream>>>(vp_w, op_w, off_w, aw_w, off_b, aw_b,
                                           out_w1, out_w2, out_w3,
                                           WVP, WOP, WOA, WM1, WM2, WM3, OAB);
    prep_combined<<<769, blk, 0, stream>>>(conv_q_w, conv_q_b, conv_v_w, conv_v_b,
                                           lin_q_w, lin_q_b, lin_v_w, lin_v_b,
                                           WQc, WVc, BQc, BVc);
    pos_kernel<<<16384, blk, 0, stream>>>(row_embed, col_embed, POS);

    // q = QT @ WQc^T + BQc; QP = q + pos     | v = VT @ WVc^T + BVc
    gmm<4, 4, false, true><<<dim3(2, 128), blk, 0, stream>>>(
        QT, WQc, BQc, nullptr, POS, QA, QPb, NQ, 256, 384);
    gmm<4, 4, false, false><<<dim3(2, 128), blk, 0, stream>>>(
        VT, WVc, BVc, nullptr, nullptr, V, nullptr, NQ, 256, 384);

    bf16* cur = QA;
    bf16* nxt = QB;
    for (int i = 0; i < 4; ++i) {
        const bf16* vin = (i < 3) ? V : cur;
        gmm<4, 4, false, false><<<dim3(2, 128), blk, 0, stream>>>(
            vin, WVP + (size_t)i * 65536, vp_b + i * 256, nullptr, nullptr,
            T2, nullptr, NQ, 256, 256);
        gmm<2, 3, false, false><<<dim3(1, 256), blk, 0, stream>>>(
            QPb, WOA + (size_t)i * 24576, OAB + i * 96, nullptr, nullptr,
            OA, nullptr, NQ, 96, 256);
        sample_kernel<<<2048, blk, 0, stream>>>(T2, OA, T1);
        gmm<4, 4, true, true><<<dim3(2, 128), blk, 0, stream>>>(
            T1, WOP + (size_t)i * 65536, op_b + i * 256, cur, POS,
            nxt, QPb, NQ, 256, 256);
        bf16* tmp = cur; cur = nxt; nxt = tmp;
    }

    // output MLP
    gmm<4, 4, false, false><<<dim3(1, 128), blk, 0, stream>>>(
        cur, WM1, out_b1, nullptr, nullptr, T1, nullptr, NQ, 128, 256);
    ln_relu<128><<<4096, blk, 0, stream>>>(T1, ln1_g, ln1_b);
    gmm<2, 2, false, false><<<dim3(1, 256), blk, 0, stream>>>(
        T1, WM2, out_b2, nullptr, nullptr, T2, nullptr, NQ, 64, 128);
    ln_relu<64><<<4096, blk, 0, stream>>>(T2, ln2_g, ln2_b);
    gmm<4, 4, false, false><<<dim3(3, 128), blk, 0, stream>>>(
        T2, WM3, out_b3, nullptr, nullptr, QT, nullptr, NQ, 384, 64);
    transpose_out<<<dim3(6, 256), blk, 0, stream>>>(QT, (float*)d_out);
}